// Round 1
// baseline (2346.439 us; speedup 1.0000x reference)
//
#include <hip/hip_runtime.h>
#include <hip/hip_bf16.h>

#define NGEN 50000
#define NBUS 80000
#define NRES 10000
#define NTOT 140000
#define EPROD 100000
#define ESERV 100000
#define ETRAN 150000
#define EBACK 50000
#define ETOT  400000
#define HID 128
#define NHEAD 4
#define NEGS 0.2f

__device__ __forceinline__ float lrelu(float x) { return x >= 0.f ? x : NEGS * x; }

// ---------------- edge setup: concat src/dst/attr ----------------
__global__ __launch_bounds__(256) void k_setup_edges(
    const int* __restrict__ eip, const int* __restrict__ eis,
    const int* __restrict__ eit, const int* __restrict__ eib,
    const float* __restrict__ eap, const float* __restrict__ eas,
    const float* __restrict__ eat, const float* __restrict__ eab,
    int* __restrict__ esrc, int* __restrict__ edst, float* __restrict__ ea_all)
{
  int e = blockIdx.x * 256 + threadIdx.x;
  if (e >= ETOT) return;
  int s, d; float a0, a1;
  if (e < EPROD) { s = eip[e]; d = eip[EPROD + e]; a0 = eap[2*e]; a1 = eap[2*e+1]; }
  else if (e < EPROD+ESERV) { int i = e - EPROD; s = eis[i]; d = eis[ESERV + i]; a0 = eas[2*i]; a1 = eas[2*i+1]; }
  else if (e < EPROD+ESERV+ETRAN) { int i = e - EPROD - ESERV; s = eit[i]; d = eit[ETRAN + i]; a0 = eat[2*i]; a1 = eat[2*i+1]; }
  else { int i = e - EPROD - ESERV - ETRAN; s = eib[i]; d = eib[EBACK + i]; a0 = eab[2*i]; a1 = eab[2*i+1]; }
  esrc[e] = s; edst[e] = d; ea_all[2*e] = a0; ea_all[2*e+1] = a1;
}

__global__ __launch_bounds__(256) void k_count(const int* __restrict__ edst, int* __restrict__ cnt)
{
  int e = blockIdx.x * 256 + threadIdx.x;
  if (e >= ETOT) return;
  atomicAdd(&cnt[edst[e]], 1);
}

// single block, 1024 threads: exclusive scan of cnt[NTOT] -> rp[NTOT+1]
__global__ __launch_bounds__(1024) void k_scan(const int* __restrict__ cnt, int* __restrict__ rp)
{
  const int T = 1024;
  int t = threadIdx.x;
  int per = (NTOT + T - 1) / T;            // 137
  int lo = t * per, hi = lo + per; if (hi > NTOT) hi = NTOT; if (lo > NTOT) lo = NTOT;
  int s = 0;
  for (int i = lo; i < hi; ++i) s += cnt[i];
  __shared__ int buf[T];
  buf[t] = s; __syncthreads();
  for (int off = 1; off < T; off <<= 1) {
    int x = (t >= off) ? buf[t - off] : 0;
    __syncthreads();
    buf[t] += x;
    __syncthreads();
  }
  int run = buf[t] - s;                    // exclusive
  for (int i = lo; i < hi; ++i) { rp[i] = run; run += cnt[i]; }
  if (t == T - 1) rp[NTOT] = run;
}

__global__ __launch_bounds__(256) void k_scatter(const int* __restrict__ edst,
    const int* __restrict__ rp, int* __restrict__ fill, int* __restrict__ elist)
{
  int e = blockIdx.x * 256 + threadIdx.x;
  if (e >= ETOT) return;
  int d = edst[e];
  int pos = rp[d] + atomicAdd(&fill[d], 1);
  elist[pos] = e;
}

// ---------------- generic fp32 GEMM: C[M,128] = op(A[M,K(lda)] @ W[K,128] + bias) ----------------
#define KC 16
__global__ __launch_bounds__(256) void k_gemm(
    const float* __restrict__ A, int lda,
    const float* __restrict__ W, const float* __restrict__ bias,
    const float* __restrict__ resid, float* __restrict__ C,
    int M, int K, int dorelu)
{
  __shared__ float As[KC][68];     // transposed A chunk, padded
  __shared__ float Ws[KC][HID];
  int tid = threadIdx.x;
  int tx = tid & 15, ty = tid >> 4;
  int row0 = blockIdx.x * 64;
  int c0 = tx * 8;
  float acc[4][8];
#pragma unroll
  for (int i = 0; i < 4; ++i)
#pragma unroll
    for (int j = 0; j < 8; ++j) acc[i][j] = 0.f;

  for (int k0 = 0; k0 < K; k0 += KC) {
#pragma unroll
    for (int j = 0; j < 4; ++j) {
      int li = tid + 256 * j;
      int r = li >> 4, kk = li & 15;
      int gr = row0 + r, gk = k0 + kk;
      As[kk][r] = (gr < M && gk < K) ? A[gr * lda + gk] : 0.f;
    }
#pragma unroll
    for (int j = 0; j < 8; ++j) {
      int li = tid + 256 * j;
      int kk = li >> 7, c = li & 127;
      int gk = k0 + kk;
      Ws[kk][c] = (gk < K) ? W[gk * HID + c] : 0.f;
    }
    __syncthreads();
#pragma unroll
    for (int kk = 0; kk < KC; ++kk) {
      float4 a4 = *(const float4*)&As[kk][ty * 4];
      float4 w0 = *(const float4*)&Ws[kk][c0];
      float4 w1 = *(const float4*)&Ws[kk][c0 + 4];
      float av[4] = {a4.x, a4.y, a4.z, a4.w};
      float wv[8] = {w0.x, w0.y, w0.z, w0.w, w1.x, w1.y, w1.z, w1.w};
#pragma unroll
      for (int i = 0; i < 4; ++i)
#pragma unroll
        for (int j = 0; j < 8; ++j) acc[i][j] += av[i] * wv[j];
    }
    __syncthreads();
  }

#pragma unroll
  for (int i = 0; i < 4; ++i) {
    int r = row0 + ty * 4 + i;
    if (r >= M) continue;
#pragma unroll
    for (int j = 0; j < 8; ++j) {
      float v = acc[i][j];
      if (bias) v += bias[c0 + j];
      if (dorelu) v = fmaxf(v, 0.f);
      if (resid) v += resid[r * HID + c0 + j];
      C[r * HID + c0 + j] = v;
    }
  }
}

// ---------------- per-layer tiny: tconst[4][4] = lrelu(ete[t]) @ attw[256:272] ----------------
__global__ void k_tconst(const float* __restrict__ ete, const float* __restrict__ attw,
                         float* __restrict__ tconst)
{
  int t = threadIdx.x;
  if (t < 16) {
    int tt = t >> 2, h = t & 3;
    float s = 0.f;
    for (int j = 0; j < 16; ++j) s += lrelu(ete[tt * 16 + j]) * attw[(256 + j) * 4 + h];
    tconst[tt * 4 + h] = s;
  }
}

// ---------------- sd/ss: per-node 128->4 projections (wave per row) ----------------
__global__ __launch_bounds__(256) void k_attproj(const float* __restrict__ xh,
    const float* __restrict__ attw, float* __restrict__ sd, float* __restrict__ ss)
{
  int wid = (blockIdx.x * 256 + threadIdx.x) >> 6;
  int lane = threadIdx.x & 63;
  if (wid >= NTOT) return;
  float2 xv = *(const float2*)&xh[wid * HID + lane * 2];
  int c = lane * 2;
  float4 wd0 = *(const float4*)&attw[c * 4];
  float4 wd1 = *(const float4*)&attw[(c + 1) * 4];
  float4 ws0 = *(const float4*)&attw[(128 + c) * 4];
  float4 ws1 = *(const float4*)&attw[(129 + c) * 4];
  float pd[4] = {xv.x * wd0.x + xv.y * wd1.x, xv.x * wd0.y + xv.y * wd1.y,
                 xv.x * wd0.z + xv.y * wd1.z, xv.x * wd0.w + xv.y * wd1.w};
  float ps[4] = {xv.x * ws0.x + xv.y * ws1.x, xv.x * ws0.y + xv.y * ws1.y,
                 xv.x * ws0.z + xv.y * ws1.z, xv.x * ws0.w + xv.y * ws1.w};
#pragma unroll
  for (int off = 32; off; off >>= 1) {
#pragma unroll
    for (int h = 0; h < 4; ++h) {
      pd[h] += __shfl_down(pd[h], off);
      ps[h] += __shfl_down(ps[h], off);
    }
  }
  if (lane == 0) {
    float4 od = {pd[0], pd[1], pd[2], pd[3]};
    float4 os = {ps[0], ps[1], ps[2], ps[3]};
    *(float4*)&sd[wid * 4] = od;
    *(float4*)&ss[wid * 4] = os;
  }
}

// ---------------- per-edge: eaee + attention logits ----------------
__global__ __launch_bounds__(256) void k_edge(
    const int* __restrict__ esrc, const int* __restrict__ edst,
    const float* __restrict__ ea_all, const float* __restrict__ eae,
    const float* __restrict__ attw, const float* __restrict__ tconst,
    const float* __restrict__ sd, const float* __restrict__ ss,
    float* __restrict__ eaeeB, float* __restrict__ a4buf)
{
  int e = blockIdx.x * 256 + threadIdx.x;
  if (e >= ETOT) return;
  int t = (e < EPROD) ? 0 : (e < EPROD + ESERV) ? 1 : (e < EPROD + ESERV + ETRAN) ? 2 : 3;
  float a0 = ea_all[2 * e], a1 = ea_all[2 * e + 1];
  int s = esrc[e], d = edst[e];
  float acc[4];
#pragma unroll
  for (int h = 0; h < 4; ++h) acc[h] = sd[d * 4 + h] + ss[s * 4 + h] + tconst[t * 4 + h];
#pragma unroll
  for (int j = 0; j < 16; ++j) {
    float v = lrelu(a0 * eae[j] + a1 * eae[16 + j]);
    eaeeB[e * 16 + j] = v;
#pragma unroll
    for (int h = 0; h < 4; ++h) acc[h] += v * attw[(272 + j) * 4 + h];
  }
  float4 out = {lrelu(acc[0]), lrelu(acc[1]), lrelu(acc[2]), lrelu(acc[3])};
  *(float4*)&a4buf[e * 4] = out;
}

// ---------------- per-dst-node aggregation (wave per node, CSR) ----------------
__global__ __launch_bounds__(256) void k_aggregate(
    const int* __restrict__ rp, const int* __restrict__ elist,
    const int* __restrict__ esrc, const float* __restrict__ a4buf,
    const float* __restrict__ eaeeB, const float* __restrict__ xh,
    float* __restrict__ agg)
{
  int wid = (blockIdx.x * 256 + threadIdx.x) >> 6;
  int lane = threadIdx.x & 63;
  if (wid >= NTOT) return;
  int beg = rp[wid], end = rp[wid + 1];

  float m0 = -INFINITY, m1 = -INFINITY, m2 = -INFINITY, m3 = -INFINITY;
  for (int i = beg; i < end; ++i) {
    int e = elist[i];
    float4 av = *(const float4*)&a4buf[e * 4];
    m0 = fmaxf(m0, av.x); m1 = fmaxf(m1, av.y); m2 = fmaxf(m2, av.z); m3 = fmaxf(m3, av.w);
  }
  float d0 = 0.f, d1 = 0.f, d2 = 0.f, d3 = 0.f;
  for (int i = beg; i < end; ++i) {
    int e = elist[i];
    float4 av = *(const float4*)&a4buf[e * 4];
    d0 += __expf(av.x - m0); d1 += __expf(av.y - m1);
    d2 += __expf(av.z - m2); d3 += __expf(av.w - m3);
  }
  d0 = 1.f / (d0 + 1e-16f); d1 = 1.f / (d1 + 1e-16f);
  d2 = 1.f / (d2 + 1e-16f); d3 = 1.f / (d3 + 1e-16f);

  float ax = 0.f, ay = 0.f, ae = 0.f;
  for (int i = beg; i < end; ++i) {
    int e = elist[i];
    float4 av = *(const float4*)&a4buf[e * 4];
    float ab = 0.25f * (__expf(av.x - m0) * d0 + __expf(av.y - m1) * d1 +
                        __expf(av.z - m2) * d2 + __expf(av.w - m3) * d3);
    int s = esrc[e];
    float2 xv = *(const float2*)&xh[s * HID + lane * 2];
    ax += ab * xv.x; ay += ab * xv.y;
    if (lane < 16) ae += ab * eaeeB[e * 16 + lane];
  }
  float2 o = {ax, ay};
  *(float2*)&agg[wid * 144 + lane * 2] = o;
  if (lane < 16) agg[wid * 144 + 128 + lane] = ae;
}

// ---------------- launch ----------------
extern "C" void kernel_launch(void* const* d_in, const int* in_sizes, int n_in,
                              void* d_out, int out_size, void* d_ws, size_t ws_size,
                              hipStream_t stream)
{
  const float* x_gen = (const float*)d_in[0];
  const float* x_bus = (const float*)d_in[1];
  const float* x_res = (const float*)d_in[2];
  const int* eip = (const int*)d_in[3];
  const int* eis = (const int*)d_in[4];
  const int* eit = (const int*)d_in[5];
  const int* eib = (const int*)d_in[6];
  const float* eap = (const float*)d_in[7];
  const float* eas = (const float*)d_in[8];
  const float* eat = (const float*)d_in[9];
  const float* eab = (const float*)d_in[10];
  const float* pW_gen = (const float*)d_in[11];
  const float* pb_gen = (const float*)d_in[12];
  const float* pW_bus = (const float*)d_in[13];
  const float* pb_bus = (const float*)d_in[14];
  const float* pW_res = (const float*)d_in[15];
  const float* pb_res = (const float*)d_in[16];

  float* out = (float*)d_out;

  char* p = (char*)d_ws;
  auto alloc = [&](size_t bytes) -> void* {
    void* r = (void*)p;
    p += (bytes + 255) & ~(size_t)255;
    return r;
  };
  int* esrc   = (int*)alloc((size_t)ETOT * 4);
  int* edst   = (int*)alloc((size_t)ETOT * 4);
  float* ea_all = (float*)alloc((size_t)ETOT * 2 * 4);
  int* cnt    = (int*)alloc((size_t)NTOT * 4);
  int* fill   = (int*)alloc((size_t)NTOT * 4);
  int* rp     = (int*)alloc((size_t)(NTOT + 1) * 4);
  int* elist  = (int*)alloc((size_t)ETOT * 4);
  float* xA   = (float*)alloc((size_t)NTOT * HID * 4);
  float* xh   = (float*)alloc((size_t)NTOT * HID * 4);
  float* sd   = (float*)alloc((size_t)NTOT * 4 * 4);
  float* ss   = (float*)alloc((size_t)NTOT * 4 * 4);
  float* eaeeB = (float*)alloc((size_t)ETOT * 16 * 4);
  float* a4buf = (float*)alloc((size_t)ETOT * 4 * 4);
  float* agg  = (float*)alloc((size_t)NTOT * 144 * 4);
  float* tconst = (float*)alloc(64);

  const int EB = (ETOT + 255) / 256;        // 1563
  const int WB = (NTOT * 64 + 255) / 256;   // 35000

  // CSR build (per call; graph is static but no cross-call caching allowed)
  hipMemsetAsync(cnt, 0, (size_t)NTOT * 4, stream);
  hipMemsetAsync(fill, 0, (size_t)NTOT * 4, stream);
  k_setup_edges<<<EB, 256, 0, stream>>>(eip, eis, eit, eib, eap, eas, eat, eab, esrc, edst, ea_all);
  k_count<<<EB, 256, 0, stream>>>(edst, cnt);
  k_scan<<<1, 1024, 0, stream>>>(cnt, rp);
  k_scatter<<<EB, 256, 0, stream>>>(edst, rp, fill, elist);

  // input projections -> xA (x0)
  k_gemm<<<(NGEN + 63) / 64, 256, 0, stream>>>(x_gen, 39, pW_gen, pb_gen, nullptr, xA, NGEN, 39, 0);
  k_gemm<<<(NBUS + 63) / 64, 256, 0, stream>>>(x_bus, 16, pW_bus, pb_bus, nullptr, xA + (size_t)NGEN * HID, NBUS, 16, 0);
  k_gemm<<<(NRES + 63) / 64, 256, 0, stream>>>(x_res, 16, pW_res, pb_res, nullptr, xA + (size_t)(NGEN + NBUS) * HID, NRES, 16, 0);

  for (int l = 0; l < 3; ++l) {
    const float* hW   = (const float*)d_in[17 + l * 6];
    const float* hb   = (const float*)d_in[18 + l * 6];
    const float* ete  = (const float*)d_in[19 + l * 6];
    const float* eae  = (const float*)d_in[20 + l * 6];
    const float* attw = (const float*)d_in[21 + l * 6];
    const float* linw = (const float*)d_in[22 + l * 6];

    const float* xin  = (l == 0) ? xA : (l == 1) ? out : xA;
    float* xout       = (l == 0) ? out : (l == 1) ? xA : out;
    const float* resid = (l == 0) ? nullptr : ((l == 1) ? out : xA);

    // HeteroLinear per node-type block
    k_gemm<<<(NGEN + 63) / 64, 256, 0, stream>>>(xin, HID, hW, hb, nullptr, xh, NGEN, HID, 0);
    k_gemm<<<(NBUS + 63) / 64, 256, 0, stream>>>(xin + (size_t)NGEN * HID, HID, hW + HID * HID, hb + HID,
                                                 nullptr, xh + (size_t)NGEN * HID, NBUS, HID, 0);
    k_gemm<<<(NRES + 63) / 64, 256, 0, stream>>>(xin + (size_t)(NGEN + NBUS) * HID, HID, hW + 2 * HID * HID, hb + 2 * HID,
                                                 nullptr, xh + (size_t)(NGEN + NBUS) * HID, NRES, HID, 0);

    k_tconst<<<1, 64, 0, stream>>>(ete, attw, tconst);
    k_attproj<<<WB, 256, 0, stream>>>(xh, attw, sd, ss);
    k_edge<<<EB, 256, 0, stream>>>(esrc, edst, ea_all, eae, attw, tconst, sd, ss, eaeeB, a4buf);
    k_aggregate<<<WB, 256, 0, stream>>>(rp, elist, esrc, a4buf, eaeeB, xh, agg);
    // out = relu(agg @ linw) (+ resid)
    k_gemm<<<(NTOT + 63) / 64, 256, 0, stream>>>(agg, 144, linw, nullptr, resid, xout, NTOT, 144, 1);
  }
}

// Round 2
// 1441.894 us; speedup vs baseline: 1.6273x; 1.6273x over previous
//
#include <hip/hip_runtime.h>
#include <hip/hip_bf16.h>

#define NGEN 50000
#define NBUS 80000
#define NRES 10000
#define NTOT 140000
#define EPROD 100000
#define ESERV 100000
#define ETRAN 150000
#define EBACK 50000
#define ETOT  400000
#define HID 128
#define NEGS 0.2f

#define NB_SCAN 547   // ceil(NTOT/256)
#define EB 1563       // ceil(ETOT/256)
#define WB 35000      // NTOT waves of 64 in 256-thread blocks

typedef __attribute__((ext_vector_type(8))) short bf16x8;
typedef __attribute__((ext_vector_type(4))) float f32x4;

__device__ __forceinline__ float lrelu(float x) { return x >= 0.f ? x : NEGS * x; }
__device__ __forceinline__ float b2f(ushort u) { union { float f; uint i; } v; v.i = (uint)u << 16; return v.f; }
__device__ __forceinline__ ushort f2b(float f) {
  union { float f; uint i; } v; v.f = f;
  return (ushort)((v.i + 0x7FFF + ((v.i >> 16) & 1)) >> 16);
}

// ---------------- edge setup ----------------
__global__ __launch_bounds__(256) void k_setup_edges(
    const int* __restrict__ eip, const int* __restrict__ eis,
    const int* __restrict__ eit, const int* __restrict__ eib,
    const float* __restrict__ eap, const float* __restrict__ eas,
    const float* __restrict__ eat, const float* __restrict__ eab,
    int* __restrict__ esrc, int* __restrict__ edst, float* __restrict__ ea_all)
{
  int e = blockIdx.x * 256 + threadIdx.x;
  if (e >= ETOT) return;
  int s, d; float a0, a1;
  if (e < EPROD) { s = eip[e]; d = eip[EPROD + e]; a0 = eap[2*e]; a1 = eap[2*e+1]; }
  else if (e < EPROD+ESERV) { int i = e - EPROD; s = eis[i]; d = eis[ESERV + i]; a0 = eas[2*i]; a1 = eas[2*i+1]; }
  else if (e < EPROD+ESERV+ETRAN) { int i = e - EPROD - ESERV; s = eit[i]; d = eit[ETRAN + i]; a0 = eat[2*i]; a1 = eat[2*i+1]; }
  else { int i = e - EPROD - ESERV - ETRAN; s = eib[i]; d = eib[EBACK + i]; a0 = eab[2*i]; a1 = eab[2*i+1]; }
  esrc[e] = s; edst[e] = d; ea_all[2*e] = a0; ea_all[2*e+1] = a1;
}

__global__ __launch_bounds__(256) void k_count(const int* __restrict__ edst, int* __restrict__ cnt)
{
  int e = blockIdx.x * 256 + threadIdx.x;
  if (e >= ETOT) return;
  atomicAdd(&cnt[edst[e]], 1);
}

// hierarchical scan: per-block exclusive scan + block sums
__global__ __launch_bounds__(256) void k_scan1(const int* __restrict__ cnt,
                                               int* __restrict__ rp, int* __restrict__ bsum)
{
  int t = threadIdx.x, i = blockIdx.x * 256 + t;
  int v = (i < NTOT) ? cnt[i] : 0;
  __shared__ int buf[256];
  buf[t] = v; __syncthreads();
  for (int off = 1; off < 256; off <<= 1) {
    int x = (t >= off) ? buf[t - off] : 0;
    __syncthreads(); buf[t] += x; __syncthreads();
  }
  if (i < NTOT) rp[i] = buf[t] - v;
  if (t == 255) bsum[blockIdx.x] = buf[255];
}

__global__ __launch_bounds__(1024) void k_scan2(int* __restrict__ bsum, int nb)
{
  int t = threadIdx.x;
  __shared__ int buf[1024];
  int v = (t < nb) ? bsum[t] : 0;
  buf[t] = v; __syncthreads();
  for (int off = 1; off < 1024; off <<= 1) {
    int x = (t >= off) ? buf[t - off] : 0;
    __syncthreads(); buf[t] += x; __syncthreads();
  }
  if (t < nb) bsum[t] = buf[t] - v;   // exclusive
}

__global__ __launch_bounds__(256) void k_scan3(int* __restrict__ rp, const int* __restrict__ bsum)
{
  int i = blockIdx.x * 256 + threadIdx.x;
  if (i < NTOT) rp[i] += bsum[blockIdx.x];
  if (i == 0) rp[NTOT] = ETOT;
}

__global__ __launch_bounds__(256) void k_scatter(const int* __restrict__ edst,
    const int* __restrict__ rp, int* __restrict__ fill, int* __restrict__ elist)
{
  int e = blockIdx.x * 256 + threadIdx.x;
  if (e >= ETOT) return;
  int d = edst[e];
  int pos = rp[d] + atomicAdd(&fill[d], 1);
  elist[pos] = e;
}

// ---------------- weight conversion: fp32 W[K,128] -> bf16 Wt[128][KP] (zero-padded) ----------------
// layout: [0)=pW_gen(KP64) [8192)=pW_bus [16384)=pW_res
// [24576 + l*73728): hW_t0,t1,t2 (KP128, 16384 each) then linw (KP192, 24576)
__global__ __launch_bounds__(256) void k_convW(
    const float* __restrict__ pg, const float* __restrict__ pb, const float* __restrict__ pr,
    const float* __restrict__ h1, const float* __restrict__ l1,
    const float* __restrict__ h2, const float* __restrict__ l2,
    const float* __restrict__ h3, const float* __restrict__ l3,
    ushort* __restrict__ dst)
{
  int idx = blockIdx.x * 256 + threadIdx.x;
  if (idx >= 245760) return;
  const float* src; int K, KP, base;
  if (idx < 24576) {
    int s = idx >> 13;
    src = (s == 0) ? pg : (s == 1) ? pb : pr;
    K = (s == 0) ? 39 : 16; KP = 64; base = s * 8192;
  } else {
    int r = idx - 24576, l = r / 73728, q = r % 73728;
    const float* h = (l == 0) ? h1 : (l == 1) ? h2 : h3;
    const float* lw = (l == 0) ? l1 : (l == 1) ? l2 : l3;
    if (q < 49152) { int t = q >> 14; src = h + t * 16384; K = 128; KP = 128; base = 24576 + l * 73728 + t * 16384; }
    else { src = lw; K = 144; KP = 192; base = 24576 + l * 73728 + 49152; }
  }
  int li = idx - base, c = li / KP, k = li % KP;
  dst[idx] = (k < K) ? f2b(src[k * 128 + c]) : (ushort)0;
}

// ---------------- bf16 MFMA GEMM: C[M,128] = op(A[M,K] @ W[K,128]) ----------------
// ABF=1: A is bf16, lda>=KP, zero-padded cols -> unconditional vector loads
// ABF=0: A is fp32, guarded scalar loads (small K)
template<int ABF>
__global__ __launch_bounds__(256) void k_mgemm(
    const void* __restrict__ Ap, int lda,
    const ushort* __restrict__ Wt, int K, int KP,
    const float* __restrict__ bias, const float* __restrict__ resid,
    float* __restrict__ Cf, ushort* __restrict__ Cb,
    int M, int dorelu)
{
  __shared__ ushort As[128][72];
  __shared__ ushort Bs[128][72];
  const int tid = threadIdx.x;
  const int lr = tid & 15, hi = (tid & 63) >> 4;
  const int w = tid >> 6;
  const int wrow = (w >> 1) * 64, wcol = (w & 1) * 64;
  const int brow = blockIdx.x * 128;

  f32x4 acc[4][4];
#pragma unroll
  for (int m = 0; m < 4; ++m)
#pragma unroll
    for (int n = 0; n < 4; ++n) acc[m][n] = (f32x4){0.f, 0.f, 0.f, 0.f};

  for (int k0 = 0; k0 < KP; k0 += 64) {
    // stage A chunk [128 rows][64 k] as bf16
#pragma unroll
    for (int p = 0; p < 8; ++p) {
      int li = tid + 256 * p;
      int row = li >> 4, c4 = (li & 15) * 4;
      int gr = brow + row, gk = k0 + c4;
      ushort4 u = make_ushort4(0, 0, 0, 0);
      if (gr < M) {
        if (ABF) {
          const ushort* A = (const ushort*)Ap;
          u = *(const ushort4*)&A[(size_t)gr * lda + gk];
        } else {
          const float* A = (const float*)Ap;
          const float* ar = A + (size_t)gr * lda;
          if (gk + 0 < K) u.x = f2b(ar[gk + 0]);
          if (gk + 1 < K) u.y = f2b(ar[gk + 1]);
          if (gk + 2 < K) u.z = f2b(ar[gk + 2]);
          if (gk + 3 < K) u.w = f2b(ar[gk + 3]);
        }
      }
      *(ushort4*)&As[row][c4] = u;
    }
    // stage B chunk: Wt[c][k0..k0+63]
#pragma unroll
    for (int p = 0; p < 8; ++p) {
      int li = tid + 256 * p;
      int row = li >> 4, c4 = (li & 15) * 4;
      *(ushort4*)&Bs[row][c4] = *(const ushort4*)&Wt[(size_t)row * KP + k0 + c4];
    }
    __syncthreads();
#pragma unroll
    for (int kk = 0; kk < 64; kk += 32) {
      bf16x8 af[4], bfv[4];
#pragma unroll
      for (int m = 0; m < 4; ++m) af[m] = *(const bf16x8*)&As[wrow + m * 16 + lr][kk + hi * 8];
#pragma unroll
      for (int n = 0; n < 4; ++n) bfv[n] = *(const bf16x8*)&Bs[wcol + n * 16 + lr][kk + hi * 8];
#pragma unroll
      for (int m = 0; m < 4; ++m)
#pragma unroll
        for (int n = 0; n < 4; ++n)
          acc[m][n] = __builtin_amdgcn_mfma_f32_16x16x32_bf16(af[m], bfv[n], acc[m][n], 0, 0, 0);
    }
    __syncthreads();
  }

  // epilogue: C/D layout col=lane&15, row=(lane>>4)*4+j
#pragma unroll
  for (int m = 0; m < 4; ++m) {
#pragma unroll
    for (int j = 0; j < 4; ++j) {
      int gr = brow + wrow + m * 16 + hi * 4 + j;
      if (gr >= M) continue;
#pragma unroll
      for (int n = 0; n < 4; ++n) {
        int col = wcol + n * 16 + lr;
        float v = acc[m][n][j];
        if (bias) v += bias[col];
        if (dorelu) v = fmaxf(v, 0.f);
        if (resid) v += resid[(size_t)gr * 128 + col];
        if (Cf) Cf[(size_t)gr * 128 + col] = v;
        if (Cb) Cb[(size_t)gr * 128 + col] = f2b(v);
      }
    }
  }
}

// ---------------- tconst[4][4] = lrelu(ete[t]) @ attw[256:272] ----------------
__global__ void k_tconst(const float* __restrict__ ete, const float* __restrict__ attw,
                         float* __restrict__ tconst)
{
  int t = threadIdx.x;
  if (t < 16) {
    int tt = t >> 2, h = t & 3;
    float s = 0.f;
    for (int j = 0; j < 16; ++j) s += lrelu(ete[tt * 16 + j]) * attw[(256 + j) * 4 + h];
    tconst[tt * 4 + h] = s;
  }
}

// ---------------- per-node 128->4 attention projections (wave per row, bf16 xh) ----------------
__global__ __launch_bounds__(256) void k_attproj(const ushort* __restrict__ xh,
    const float* __restrict__ attw, float* __restrict__ sd, float* __restrict__ ss)
{
  int wid = (blockIdx.x * 256 + threadIdx.x) >> 6;
  int lane = threadIdx.x & 63;
  if (wid >= NTOT) return;
  ushort2 xu = *(const ushort2*)&xh[(size_t)wid * HID + lane * 2];
  float x0 = b2f(xu.x), x1 = b2f(xu.y);
  int c = lane * 2;
  float4 wd0 = *(const float4*)&attw[c * 4];
  float4 wd1 = *(const float4*)&attw[(c + 1) * 4];
  float4 ws0 = *(const float4*)&attw[(128 + c) * 4];
  float4 ws1 = *(const float4*)&attw[(129 + c) * 4];
  float pd[4] = {x0 * wd0.x + x1 * wd1.x, x0 * wd0.y + x1 * wd1.y,
                 x0 * wd0.z + x1 * wd1.z, x0 * wd0.w + x1 * wd1.w};
  float ps[4] = {x0 * ws0.x + x1 * ws1.x, x0 * ws0.y + x1 * ws1.y,
                 x0 * ws0.z + x1 * ws1.z, x0 * ws0.w + x1 * ws1.w};
#pragma unroll
  for (int off = 32; off; off >>= 1)
#pragma unroll
    for (int h = 0; h < 4; ++h) {
      pd[h] += __shfl_down(pd[h], off);
      ps[h] += __shfl_down(ps[h], off);
    }
  if (lane == 0) {
    float4 od = {pd[0], pd[1], pd[2], pd[3]};
    float4 os = {ps[0], ps[1], ps[2], ps[3]};
    *(float4*)&sd[wid * 4] = od;
    *(float4*)&ss[wid * 4] = os;
  }
}

// ---------------- per-edge: eaee (bf16) + attention logits ----------------
__global__ __launch_bounds__(256) void k_edge(
    const int* __restrict__ esrc, const int* __restrict__ edst,
    const float* __restrict__ ea_all, const float* __restrict__ eae,
    const float* __restrict__ attw, const float* __restrict__ tconst,
    const float* __restrict__ sd, const float* __restrict__ ss,
    ushort* __restrict__ eaeeB, float* __restrict__ a4buf)
{
  int e = blockIdx.x * 256 + threadIdx.x;
  if (e >= ETOT) return;
  int t = (e < EPROD) ? 0 : (e < EPROD + ESERV) ? 1 : (e < EPROD + ESERV + ETRAN) ? 2 : 3;
  float a0 = ea_all[2 * e], a1 = ea_all[2 * e + 1];
  int s = esrc[e], d = edst[e];
  float acc[4];
#pragma unroll
  for (int h = 0; h < 4; ++h) acc[h] = sd[d * 4 + h] + ss[s * 4 + h] + tconst[t * 4 + h];
  ushort us[16];
#pragma unroll
  for (int j = 0; j < 16; ++j) {
    float v = lrelu(a0 * eae[j] + a1 * eae[16 + j]);
    us[j] = f2b(v);
#pragma unroll
    for (int h = 0; h < 4; ++h) acc[h] += v * attw[(272 + j) * 4 + h];
  }
  *(ushort4*)&eaeeB[(size_t)e * 16 + 0]  = make_ushort4(us[0], us[1], us[2], us[3]);
  *(ushort4*)&eaeeB[(size_t)e * 16 + 4]  = make_ushort4(us[4], us[5], us[6], us[7]);
  *(ushort4*)&eaeeB[(size_t)e * 16 + 8]  = make_ushort4(us[8], us[9], us[10], us[11]);
  *(ushort4*)&eaeeB[(size_t)e * 16 + 12] = make_ushort4(us[12], us[13], us[14], us[15]);
  float4 out = {lrelu(acc[0]), lrelu(acc[1]), lrelu(acc[2]), lrelu(acc[3])};
  *(float4*)&a4buf[e * 4] = out;
}

// ---------------- per-dst-node aggregation (wave per node) -> agg bf16 [N][192] ----------------
__global__ __launch_bounds__(256) void k_aggregate(
    const int* __restrict__ rp, const int* __restrict__ elist,
    const int* __restrict__ esrc, const float* __restrict__ a4buf,
    const ushort* __restrict__ eaeeB, const ushort* __restrict__ xh,
    ushort* __restrict__ agg)
{
  int wid = (blockIdx.x * 256 + threadIdx.x) >> 6;
  int lane = threadIdx.x & 63;
  if (wid >= NTOT) return;
  int beg = rp[wid], end = rp[wid + 1];

  float m0 = -INFINITY, m1 = -INFINITY, m2 = -INFINITY, m3 = -INFINITY;
  for (int i = beg; i < end; ++i) {
    int e = elist[i];
    float4 av = *(const float4*)&a4buf[e * 4];
    m0 = fmaxf(m0, av.x); m1 = fmaxf(m1, av.y); m2 = fmaxf(m2, av.z); m3 = fmaxf(m3, av.w);
  }
  float d0 = 0.f, d1 = 0.f, d2 = 0.f, d3 = 0.f;
  for (int i = beg; i < end; ++i) {
    int e = elist[i];
    float4 av = *(const float4*)&a4buf[e * 4];
    d0 += __expf(av.x - m0); d1 += __expf(av.y - m1);
    d2 += __expf(av.z - m2); d3 += __expf(av.w - m3);
  }
  d0 = 1.f / (d0 + 1e-16f); d1 = 1.f / (d1 + 1e-16f);
  d2 = 1.f / (d2 + 1e-16f); d3 = 1.f / (d3 + 1e-16f);

  float ax = 0.f, ay = 0.f, ae = 0.f;
  for (int i = beg; i < end; ++i) {
    int e = elist[i];
    float4 av = *(const float4*)&a4buf[e * 4];
    float ab = 0.25f * (__expf(av.x - m0) * d0 + __expf(av.y - m1) * d1 +
                        __expf(av.z - m2) * d2 + __expf(av.w - m3) * d3);
    int s = elist ? esrc[e] : 0;
    ushort2 xu = *(const ushort2*)&xh[(size_t)s * HID + lane * 2];
    ax += ab * b2f(xu.x); ay += ab * b2f(xu.y);
    if (lane < 16) ae += ab * b2f(eaeeB[(size_t)e * 16 + lane]);
  }
  size_t rb = (size_t)wid * 192;
  *(ushort2*)&agg[rb + lane * 2] = make_ushort2(f2b(ax), f2b(ay));
  if (lane < 16) agg[rb + 128 + lane] = f2b(ae);
  if (lane < 24) *(ushort2*)&agg[rb + 144 + lane * 2] = make_ushort2(0, 0);  // zero K-pad
}

// ---------------- launch ----------------
extern "C" void kernel_launch(void* const* d_in, const int* in_sizes, int n_in,
                              void* d_out, int out_size, void* d_ws, size_t ws_size,
                              hipStream_t stream)
{
  const float* x_gen = (const float*)d_in[0];
  const float* x_bus = (const float*)d_in[1];
  const float* x_res = (const float*)d_in[2];
  const int* eip = (const int*)d_in[3];
  const int* eis = (const int*)d_in[4];
  const int* eit = (const int*)d_in[5];
  const int* eib = (const int*)d_in[6];
  const float* eap = (const float*)d_in[7];
  const float* eas = (const float*)d_in[8];
  const float* eat = (const float*)d_in[9];
  const float* eab = (const float*)d_in[10];
  const float* pW_gen = (const float*)d_in[11];
  const float* pb_gen = (const float*)d_in[12];
  const float* pW_bus = (const float*)d_in[13];
  const float* pb_bus = (const float*)d_in[14];
  const float* pW_res = (const float*)d_in[15];
  const float* pb_res = (const float*)d_in[16];

  float* out = (float*)d_out;

  char* p = (char*)d_ws;
  auto alloc = [&](size_t bytes) -> void* {
    void* r = (void*)p;
    p += (bytes + 255) & ~(size_t)255;
    return r;
  };
  int* esrc    = (int*)alloc((size_t)ETOT * 4);
  int* edst    = (int*)alloc((size_t)ETOT * 4);
  float* ea_all = (float*)alloc((size_t)ETOT * 2 * 4);
  int* cnt     = (int*)alloc((size_t)NTOT * 4);
  int* fill    = (int*)alloc((size_t)NTOT * 4);
  int* rp      = (int*)alloc((size_t)(NTOT + 1) * 4);
  int* bsum    = (int*)alloc(1024 * 4);
  int* elist   = (int*)alloc((size_t)ETOT * 4);
  ushort* Wt   = (ushort*)alloc((size_t)245760 * 2);
  float* xA    = (float*)alloc((size_t)NTOT * HID * 4);    // fp32 layer ping
  ushort* x_bf = (ushort*)alloc((size_t)NTOT * HID * 2);   // bf16 layer input
  ushort* xh_bf = (ushort*)alloc((size_t)NTOT * HID * 2);  // bf16 hetero output
  float* sd    = (float*)alloc((size_t)NTOT * 4 * 4);
  float* ss    = (float*)alloc((size_t)NTOT * 4 * 4);
  ushort* eaeeB = (ushort*)alloc((size_t)ETOT * 16 * 2);
  float* a4buf = (float*)alloc((size_t)ETOT * 4 * 4);
  ushort* agg  = (ushort*)alloc((size_t)NTOT * 192 * 2);
  float* tconst = (float*)alloc(64);

  // ---- CSR build ----
  hipMemsetAsync(cnt, 0, (size_t)NTOT * 4, stream);
  hipMemsetAsync(fill, 0, (size_t)NTOT * 4, stream);
  k_setup_edges<<<EB, 256, 0, stream>>>(eip, eis, eit, eib, eap, eas, eat, eab, esrc, edst, ea_all);
  k_count<<<EB, 256, 0, stream>>>(edst, cnt);
  k_scan1<<<NB_SCAN, 256, 0, stream>>>(cnt, rp, bsum);
  k_scan2<<<1, 1024, 0, stream>>>(bsum, NB_SCAN);
  k_scan3<<<NB_SCAN, 256, 0, stream>>>(rp, bsum);
  k_scatter<<<EB, 256, 0, stream>>>(edst, rp, fill, elist);

  // ---- weight conversion ----
  k_convW<<<960, 256, 0, stream>>>(pW_gen, pW_bus, pW_res,
      (const float*)d_in[17], (const float*)d_in[22],
      (const float*)d_in[23], (const float*)d_in[28],
      (const float*)d_in[29], (const float*)d_in[34], Wt);

  // ---- input projections -> xA fp32 + x_bf bf16 ----
  k_mgemm<0><<<(NGEN + 127) / 128, 256, 0, stream>>>(x_gen, 39, Wt + 0, 39, 64,
      pb_gen, nullptr, xA, x_bf, NGEN, 0);
  k_mgemm<0><<<(NBUS + 127) / 128, 256, 0, stream>>>(x_bus, 16, Wt + 8192, 16, 64,
      pb_bus, nullptr, xA + (size_t)NGEN * HID, x_bf + (size_t)NGEN * HID, NBUS, 0);
  k_mgemm<0><<<(NRES + 127) / 128, 256, 0, stream>>>(x_res, 16, Wt + 16384, 16, 64,
      pb_res, nullptr, xA + (size_t)(NGEN + NBUS) * HID, x_bf + (size_t)(NGEN + NBUS) * HID, NRES, 0);

  for (int l = 0; l < 3; ++l) {
    const float* hb   = (const float*)d_in[18 + l * 6];
    const float* ete  = (const float*)d_in[19 + l * 6];
    const float* eae  = (const float*)d_in[20 + l * 6];
    const float* attw = (const float*)d_in[21 + l * 6];
    const ushort* WtH = Wt + 24576 + l * 73728;
    const ushort* WtL = Wt + 24576 + l * 73728 + 49152;

    // fp32 residual / output routing: x1->out, x2->xA, x3->out
    const float* resid = (l == 0) ? nullptr : (l == 1) ? out : xA;
    float* xoutf       = (l == 0) ? out : (l == 1) ? xA : out;
    ushort* xoutb      = (l == 2) ? nullptr : x_bf;

    // HeteroLinear per node-type block: x_bf -> xh_bf
    k_mgemm<1><<<(NGEN + 127) / 128, 256, 0, stream>>>(x_bf, 128, WtH, 128, 128,
        hb, nullptr, nullptr, xh_bf, NGEN, 0);
    k_mgemm<1><<<(NBUS + 127) / 128, 256, 0, stream>>>(x_bf + (size_t)NGEN * HID, 128, WtH + 16384, 128, 128,
        hb + HID, nullptr, nullptr, xh_bf + (size_t)NGEN * HID, NBUS, 0);
    k_mgemm<1><<<(NRES + 127) / 128, 256, 0, stream>>>(x_bf + (size_t)(NGEN + NBUS) * HID, 128, WtH + 32768, 128, 128,
        hb + 2 * HID, nullptr, nullptr, xh_bf + (size_t)(NGEN + NBUS) * HID, NRES, 0);

    k_tconst<<<1, 64, 0, stream>>>(ete, attw, tconst);
    k_attproj<<<WB, 256, 0, stream>>>(xh_bf, attw, sd, ss);
    k_edge<<<EB, 256, 0, stream>>>(esrc, edst, ea_all, eae, attw, tconst, sd, ss, eaeeB, a4buf);
    k_aggregate<<<WB, 256, 0, stream>>>(rp, elist, esrc, a4buf, eaeeB, xh_bf, agg);

    // xout = relu(agg @ linw) + resid
    k_mgemm<1><<<(NTOT + 127) / 128, 256, 0, stream>>>(agg, 192, WtL, 144, 192,
        nullptr, resid, xoutf, xoutb, NTOT, 1);
  }
}

// Round 3
// 960.271 us; speedup vs baseline: 2.4435x; 1.5015x over previous
//
#include <hip/hip_runtime.h>
#include <hip/hip_bf16.h>

#define NGEN 50000
#define NBUS 80000
#define NRES 10000
#define NTOT 140000
#define EPROD 100000
#define ESERV 100000
#define ETRAN 150000
#define EBACK 50000
#define ETOT  400000
#define HID 128
#define NEGS 0.2f

#define NB_SCAN 547   // ceil(NTOT/256)
#define EB 1563       // ceil(ETOT/256)
#define WB 35000      // NTOT waves of 64 in 256-thread blocks

typedef __attribute__((ext_vector_type(8))) short bf16x8;
typedef __attribute__((ext_vector_type(4))) float f32x4;

__device__ __forceinline__ float lrelu(float x) { return x >= 0.f ? x : NEGS * x; }
__device__ __forceinline__ float b2f(ushort u) { union { float f; uint i; } v; v.i = (uint)u << 16; return v.f; }
__device__ __forceinline__ ushort f2b(float f) {
  union { float f; uint i; } v; v.f = f;
  return (ushort)((v.i + 0x7FFF + ((v.i >> 16) & 1)) >> 16);
}

// ---------------- edge setup (+ degree count) ----------------
__global__ __launch_bounds__(256) void k_setup_edges(
    const int* __restrict__ eip, const int* __restrict__ eis,
    const int* __restrict__ eit, const int* __restrict__ eib,
    const float* __restrict__ eap, const float* __restrict__ eas,
    const float* __restrict__ eat, const float* __restrict__ eab,
    int* __restrict__ esrc, int* __restrict__ edst, float* __restrict__ ea_all,
    int* __restrict__ cnt)
{
  int e = blockIdx.x * 256 + threadIdx.x;
  if (e >= ETOT) return;
  int s, d; float a0, a1;
  if (e < EPROD) { s = eip[e]; d = eip[EPROD + e]; a0 = eap[2*e]; a1 = eap[2*e+1]; }
  else if (e < EPROD+ESERV) { int i = e - EPROD; s = eis[i]; d = eis[ESERV + i]; a0 = eas[2*i]; a1 = eas[2*i+1]; }
  else if (e < EPROD+ESERV+ETRAN) { int i = e - EPROD - ESERV; s = eit[i]; d = eit[ETRAN + i]; a0 = eat[2*i]; a1 = eat[2*i+1]; }
  else { int i = e - EPROD - ESERV - ETRAN; s = eib[i]; d = eib[EBACK + i]; a0 = eab[2*i]; a1 = eab[2*i+1]; }
  esrc[e] = s; edst[e] = d; ea_all[2*e] = a0; ea_all[2*e+1] = a1;
  atomicAdd(&cnt[d], 1);
}

// hierarchical scan
__global__ __launch_bounds__(256) void k_scan1(const int* __restrict__ cnt,
                                               int* __restrict__ rp, int* __restrict__ bsum)
{
  int t = threadIdx.x, i = blockIdx.x * 256 + t;
  int v = (i < NTOT) ? cnt[i] : 0;
  __shared__ int buf[256];
  buf[t] = v; __syncthreads();
  for (int off = 1; off < 256; off <<= 1) {
    int x = (t >= off) ? buf[t - off] : 0;
    __syncthreads(); buf[t] += x; __syncthreads();
  }
  if (i < NTOT) rp[i] = buf[t] - v;
  if (t == 255) bsum[blockIdx.x] = buf[255];
}

__global__ __launch_bounds__(1024) void k_scan2(int* __restrict__ bsum, int nb)
{
  int t = threadIdx.x;
  __shared__ int buf[1024];
  int v = (t < nb) ? bsum[t] : 0;
  buf[t] = v; __syncthreads();
  for (int off = 1; off < 1024; off <<= 1) {
    int x = (t >= off) ? buf[t - off] : 0;
    __syncthreads(); buf[t] += x; __syncthreads();
  }
  if (t < nb) bsum[t] = buf[t] - v;
}

__global__ __launch_bounds__(256) void k_scan3(int* __restrict__ rp, const int* __restrict__ bsum)
{
  int i = blockIdx.x * 256 + threadIdx.x;
  if (i < NTOT) rp[i] += bsum[blockIdx.x];
  if (i == 0) rp[NTOT] = ETOT;
}

__global__ __launch_bounds__(256) void k_scatter(const int* __restrict__ edst,
    const int* __restrict__ rp, int* __restrict__ fill, int* __restrict__ elist)
{
  int e = blockIdx.x * 256 + threadIdx.x;
  if (e >= ETOT) return;
  int d = edst[e];
  int pos = rp[d] + atomicAdd(&fill[d], 1);
  elist[pos] = e;
}

// ---------------- weight conversion ----------------
__global__ __launch_bounds__(256) void k_convW(
    const float* __restrict__ pg, const float* __restrict__ pb, const float* __restrict__ pr,
    const float* __restrict__ h1, const float* __restrict__ l1,
    const float* __restrict__ h2, const float* __restrict__ l2,
    const float* __restrict__ h3, const float* __restrict__ l3,
    ushort* __restrict__ dst)
{
  int idx = blockIdx.x * 256 + threadIdx.x;
  if (idx >= 245760) return;
  const float* src; int K, KP, base;
  if (idx < 24576) {
    int s = idx >> 13;
    src = (s == 0) ? pg : (s == 1) ? pb : pr;
    K = (s == 0) ? 39 : 16; KP = 64; base = s * 8192;
  } else {
    int r = idx - 24576, l = r / 73728, q = r % 73728;
    const float* h = (l == 0) ? h1 : (l == 1) ? h2 : h3;
    const float* lw = (l == 0) ? l1 : (l == 1) ? l2 : l3;
    if (q < 49152) { int t = q >> 14; src = h + t * 16384; K = 128; KP = 128; base = 24576 + l * 73728 + t * 16384; }
    else { src = lw; K = 144; KP = 192; base = 24576 + l * 73728 + 49152; }
  }
  int li = idx - base, c = li / KP, k = li % KP;
  dst[idx] = (k < K) ? f2b(src[k * 128 + c]) : (ushort)0;
}

// ---------------- segmented bf16 MFMA GEMM: Cb[rbase+r][128] = bf16(A_seg @ W_seg + bias) ----------------
struct Seg {
  const void* A; const ushort* Wt; const float* bias;
  int lda, K, M, nb, rbase;
};

template<int ABF>
__global__ __launch_bounds__(256) void k_mgemm3(Seg s0, Seg s1, Seg s2, int KP, ushort* __restrict__ Cb)
{
  __shared__ ushort As[128][72];
  __shared__ ushort Bs[128][72];
  int bid = blockIdx.x;
  Seg sg = s0;
  if (bid >= s0.nb + s1.nb) { sg = s2; bid -= s0.nb + s1.nb; }
  else if (bid >= s0.nb) { sg = s1; bid -= s0.nb; }

  const int tid = threadIdx.x;
  const int lr = tid & 15, hi = (tid & 63) >> 4;
  const int w = tid >> 6;
  const int wrow = (w >> 1) * 64, wcol = (w & 1) * 64;
  const int brow = bid * 128;

  f32x4 acc[4][4];
#pragma unroll
  for (int m = 0; m < 4; ++m)
#pragma unroll
    for (int n = 0; n < 4; ++n) acc[m][n] = (f32x4){0.f, 0.f, 0.f, 0.f};

  for (int k0 = 0; k0 < KP; k0 += 64) {
#pragma unroll
    for (int p = 0; p < 8; ++p) {
      int li = tid + 256 * p;
      int row = li >> 4, c4 = (li & 15) * 4;
      int gr = brow + row, gk = k0 + c4;
      ushort4 u = make_ushort4(0, 0, 0, 0);
      if (gr < sg.M) {
        if (ABF) {
          const ushort* A = (const ushort*)sg.A;
          u = *(const ushort4*)&A[(size_t)gr * sg.lda + gk];
        } else {
          const float* A = (const float*)sg.A;
          const float* ar = A + (size_t)gr * sg.lda;
          if (gk + 0 < sg.K) u.x = f2b(ar[gk + 0]);
          if (gk + 1 < sg.K) u.y = f2b(ar[gk + 1]);
          if (gk + 2 < sg.K) u.z = f2b(ar[gk + 2]);
          if (gk + 3 < sg.K) u.w = f2b(ar[gk + 3]);
        }
      }
      *(ushort4*)&As[row][c4] = u;
    }
#pragma unroll
    for (int p = 0; p < 8; ++p) {
      int li = tid + 256 * p;
      int row = li >> 4, c4 = (li & 15) * 4;
      *(ushort4*)&Bs[row][c4] = *(const ushort4*)&sg.Wt[(size_t)row * KP + k0 + c4];
    }
    __syncthreads();
#pragma unroll
    for (int kk = 0; kk < 64; kk += 32) {
      bf16x8 af[4], bfv[4];
#pragma unroll
      for (int m = 0; m < 4; ++m) af[m] = *(const bf16x8*)&As[wrow + m * 16 + lr][kk + hi * 8];
#pragma unroll
      for (int n = 0; n < 4; ++n) bfv[n] = *(const bf16x8*)&Bs[wcol + n * 16 + lr][kk + hi * 8];
#pragma unroll
      for (int m = 0; m < 4; ++m)
#pragma unroll
        for (int n = 0; n < 4; ++n)
          acc[m][n] = __builtin_amdgcn_mfma_f32_16x16x32_bf16(af[m], bfv[n], acc[m][n], 0, 0, 0);
    }
    __syncthreads();
  }

#pragma unroll
  for (int m = 0; m < 4; ++m) {
#pragma unroll
    for (int j = 0; j < 4; ++j) {
      int gr = brow + wrow + m * 16 + hi * 4 + j;
      if (gr >= sg.M) continue;
#pragma unroll
      for (int n = 0; n < 4; ++n) {
        int col = wcol + n * 16 + lr;
        float v = acc[m][n][j] + sg.bias[col];
        Cb[(size_t)(sg.rbase + gr) * 128 + col] = f2b(v);
      }
    }
  }
}

// ---------------- plain GEMM for linw: C = relu(agg @ linw) + resid ----------------
__global__ __launch_bounds__(256) void k_mgemm(
    const ushort* __restrict__ Ab, int lda,
    const ushort* __restrict__ Wt, int KP,
    const float* __restrict__ resid,
    float* __restrict__ Cf, ushort* __restrict__ Cb, int M)
{
  __shared__ ushort As[128][72];
  __shared__ ushort Bs[128][72];
  const int tid = threadIdx.x;
  const int lr = tid & 15, hi = (tid & 63) >> 4;
  const int w = tid >> 6;
  const int wrow = (w >> 1) * 64, wcol = (w & 1) * 64;
  const int brow = blockIdx.x * 128;

  f32x4 acc[4][4];
#pragma unroll
  for (int m = 0; m < 4; ++m)
#pragma unroll
    for (int n = 0; n < 4; ++n) acc[m][n] = (f32x4){0.f, 0.f, 0.f, 0.f};

  for (int k0 = 0; k0 < KP; k0 += 64) {
#pragma unroll
    for (int p = 0; p < 8; ++p) {
      int li = tid + 256 * p;
      int row = li >> 4, c4 = (li & 15) * 4;
      int gr = brow + row;
      ushort4 u = make_ushort4(0, 0, 0, 0);
      if (gr < M) u = *(const ushort4*)&Ab[(size_t)gr * lda + k0 + c4];
      *(ushort4*)&As[row][c4] = u;
    }
#pragma unroll
    for (int p = 0; p < 8; ++p) {
      int li = tid + 256 * p;
      int row = li >> 4, c4 = (li & 15) * 4;
      *(ushort4*)&Bs[row][c4] = *(const ushort4*)&Wt[(size_t)row * KP + k0 + c4];
    }
    __syncthreads();
#pragma unroll
    for (int kk = 0; kk < 64; kk += 32) {
      bf16x8 af[4], bfv[4];
#pragma unroll
      for (int m = 0; m < 4; ++m) af[m] = *(const bf16x8*)&As[wrow + m * 16 + lr][kk + hi * 8];
#pragma unroll
      for (int n = 0; n < 4; ++n) bfv[n] = *(const bf16x8*)&Bs[wcol + n * 16 + lr][kk + hi * 8];
#pragma unroll
      for (int m = 0; m < 4; ++m)
#pragma unroll
        for (int n = 0; n < 4; ++n)
          acc[m][n] = __builtin_amdgcn_mfma_f32_16x16x32_bf16(af[m], bfv[n], acc[m][n], 0, 0, 0);
    }
    __syncthreads();
  }

#pragma unroll
  for (int m = 0; m < 4; ++m) {
#pragma unroll
    for (int j = 0; j < 4; ++j) {
      int gr = brow + wrow + m * 16 + hi * 4 + j;
      if (gr >= M) continue;
#pragma unroll
      for (int n = 0; n < 4; ++n) {
        int col = wcol + n * 16 + lr;
        float v = fmaxf(acc[m][n][j], 0.f);
        if (resid) v += resid[(size_t)gr * 128 + col];
        if (Cf) Cf[(size_t)gr * 128 + col] = v;
        if (Cb) Cb[(size_t)gr * 128 + col] = f2b(v);
      }
    }
  }
}

// ---------------- tconst ----------------
__global__ void k_tconst(const float* __restrict__ ete, const float* __restrict__ attw,
                         float* __restrict__ tconst)
{
  int t = threadIdx.x;
  if (t < 16) {
    int tt = t >> 2, h = t & 3;
    float s = 0.f;
    for (int j = 0; j < 16; ++j) s += lrelu(ete[tt * 16 + j]) * attw[(256 + j) * 4 + h];
    tconst[tt * 4 + h] = s;
  }
}

// ---------------- per-node 128->4 attention projections ----------------
__global__ __launch_bounds__(256) void k_attproj(const ushort* __restrict__ xh,
    const float* __restrict__ attw, float* __restrict__ sd, float* __restrict__ ss)
{
  int wid = (blockIdx.x * 256 + threadIdx.x) >> 6;
  int lane = threadIdx.x & 63;
  if (wid >= NTOT) return;
  ushort2 xu = *(const ushort2*)&xh[(size_t)wid * HID + lane * 2];
  float x0 = b2f(xu.x), x1 = b2f(xu.y);
  int c = lane * 2;
  float4 wd0 = *(const float4*)&attw[c * 4];
  float4 wd1 = *(const float4*)&attw[(c + 1) * 4];
  float4 ws0 = *(const float4*)&attw[(128 + c) * 4];
  float4 ws1 = *(const float4*)&attw[(129 + c) * 4];
  float pd[4] = {x0 * wd0.x + x1 * wd1.x, x0 * wd0.y + x1 * wd1.y,
                 x0 * wd0.z + x1 * wd1.z, x0 * wd0.w + x1 * wd1.w};
  float ps[4] = {x0 * ws0.x + x1 * ws1.x, x0 * ws0.y + x1 * ws1.y,
                 x0 * ws0.z + x1 * ws1.z, x0 * ws0.w + x1 * ws1.w};
#pragma unroll
  for (int off = 32; off; off >>= 1)
#pragma unroll
    for (int h = 0; h < 4; ++h) {
      pd[h] += __shfl_down(pd[h], off);
      ps[h] += __shfl_down(ps[h], off);
    }
  if (lane == 0) {
    float4 od = {pd[0], pd[1], pd[2], pd[3]};
    float4 os = {ps[0], ps[1], ps[2], ps[3]};
    *(float4*)&sd[wid * 4] = od;
    *(float4*)&ss[wid * 4] = os;
  }
}

// ---------------- per-edge: eaee (bf16) + attention logits ----------------
__global__ __launch_bounds__(256) void k_edge(
    const int* __restrict__ esrc, const int* __restrict__ edst,
    const float* __restrict__ ea_all, const float* __restrict__ eae,
    const float* __restrict__ attw, const float* __restrict__ tconst,
    const float* __restrict__ sd, const float* __restrict__ ss,
    ushort* __restrict__ eaeeB, float* __restrict__ a4buf)
{
  int e = blockIdx.x * 256 + threadIdx.x;
  if (e >= ETOT) return;
  int t = (e < EPROD) ? 0 : (e < EPROD + ESERV) ? 1 : (e < EPROD + ESERV + ETRAN) ? 2 : 3;
  float a0 = ea_all[2 * e], a1 = ea_all[2 * e + 1];
  int s = esrc[e], d = edst[e];
  float acc[4];
#pragma unroll
  for (int h = 0; h < 4; ++h) acc[h] = sd[d * 4 + h] + ss[s * 4 + h] + tconst[t * 4 + h];
  ushort us[16];
#pragma unroll
  for (int j = 0; j < 16; ++j) {
    float v = lrelu(a0 * eae[j] + a1 * eae[16 + j]);
    us[j] = f2b(v);
#pragma unroll
    for (int h = 0; h < 4; ++h) acc[h] += v * attw[(272 + j) * 4 + h];
  }
  *(ushort4*)&eaeeB[(size_t)e * 16 + 0]  = make_ushort4(us[0], us[1], us[2], us[3]);
  *(ushort4*)&eaeeB[(size_t)e * 16 + 4]  = make_ushort4(us[4], us[5], us[6], us[7]);
  *(ushort4*)&eaeeB[(size_t)e * 16 + 8]  = make_ushort4(us[8], us[9], us[10], us[11]);
  *(ushort4*)&eaeeB[(size_t)e * 16 + 12] = make_ushort4(us[12], us[13], us[14], us[15]);
  float4 out = {lrelu(acc[0]), lrelu(acc[1]), lrelu(acc[2]), lrelu(acc[3])};
  *(float4*)&a4buf[e * 4] = out;
}

// ---------------- per-dst-node aggregation: lane-parallel softmax + single gather pass ----------------
__global__ __launch_bounds__(256) void k_aggregate(
    const int* __restrict__ rp, const int* __restrict__ elist,
    const int* __restrict__ esrc, const float* __restrict__ a4buf,
    const ushort* __restrict__ eaeeB, const ushort* __restrict__ xh,
    ushort* __restrict__ agg)
{
  int wid = (blockIdx.x * 256 + threadIdx.x) >> 6;
  int lane = threadIdx.x & 63;
  if (wid >= NTOT) return;
  int beg = rp[wid], end = rp[wid + 1];
  int deg = end - beg;
  size_t rb = (size_t)wid * 192;

  if (deg == 0) {
    *(ushort2*)&agg[rb + lane * 2] = make_ushort2(0, 0);
    if (lane < 32) *(ushort2*)&agg[rb + 128 + lane * 2] = make_ushort2(0, 0);
    return;
  }

  float ax = 0.f, ay = 0.f, ae = 0.f;

  if (deg <= 64) {
    // lane i owns edge i
    int e = 0, s = 0;
    float4 av = make_float4(-INFINITY, -INFINITY, -INFINITY, -INFINITY);
    if (lane < deg) {
      e = elist[beg + lane];
      s = esrc[e];
      av = *(const float4*)&a4buf[e * 4];
    }
    float m0 = av.x, m1 = av.y, m2 = av.z, m3 = av.w;
#pragma unroll
    for (int mask = 32; mask; mask >>= 1) {
      m0 = fmaxf(m0, __shfl_xor(m0, mask));
      m1 = fmaxf(m1, __shfl_xor(m1, mask));
      m2 = fmaxf(m2, __shfl_xor(m2, mask));
      m3 = fmaxf(m3, __shfl_xor(m3, mask));
    }
    float p0 = 0.f, p1 = 0.f, p2 = 0.f, p3 = 0.f;
    if (lane < deg) {
      p0 = __expf(av.x - m0); p1 = __expf(av.y - m1);
      p2 = __expf(av.z - m2); p3 = __expf(av.w - m3);
    }
    float d0 = p0, d1 = p1, d2 = p2, d3 = p3;
#pragma unroll
    for (int mask = 32; mask; mask >>= 1) {
      d0 += __shfl_xor(d0, mask);
      d1 += __shfl_xor(d1, mask);
      d2 += __shfl_xor(d2, mask);
      d3 += __shfl_xor(d3, mask);
    }
    float ab = 0.f;
    if (lane < deg)
      ab = 0.25f * (p0 / (d0 + 1e-16f) + p1 / (d1 + 1e-16f) +
                    p2 / (d2 + 1e-16f) + p3 / (d3 + 1e-16f));

    // single gather pass, unrolled by 4 (invalid lanes carry ab=0, e=s=0)
    for (int j0 = 0; j0 < deg; j0 += 4) {
      float ab0 = __shfl(ab, j0), ab1 = __shfl(ab, j0 + 1);
      float ab2 = __shfl(ab, j0 + 2), ab3 = __shfl(ab, j0 + 3);
      int s0 = __shfl(s, j0), s1 = __shfl(s, j0 + 1);
      int s2 = __shfl(s, j0 + 2), s3 = __shfl(s, j0 + 3);
      int e0 = __shfl(e, j0), e1 = __shfl(e, j0 + 1);
      int e2 = __shfl(e, j0 + 2), e3 = __shfl(e, j0 + 3);
      ushort2 x0 = *(const ushort2*)&xh[(size_t)s0 * HID + lane * 2];
      ushort2 x1 = *(const ushort2*)&xh[(size_t)s1 * HID + lane * 2];
      ushort2 x2 = *(const ushort2*)&xh[(size_t)s2 * HID + lane * 2];
      ushort2 x3 = *(const ushort2*)&xh[(size_t)s3 * HID + lane * 2];
      ushort q0 = 0, q1 = 0, q2 = 0, q3 = 0;
      if (lane < 16) {
        q0 = eaeeB[(size_t)e0 * 16 + lane];
        q1 = eaeeB[(size_t)e1 * 16 + lane];
        q2 = eaeeB[(size_t)e2 * 16 + lane];
        q3 = eaeeB[(size_t)e3 * 16 + lane];
      }
      ax += ab0 * b2f(x0.x) + ab1 * b2f(x1.x) + ab2 * b2f(x2.x) + ab3 * b2f(x3.x);
      ay += ab0 * b2f(x0.y) + ab1 * b2f(x1.y) + ab2 * b2f(x2.y) + ab3 * b2f(x3.y);
      ae += ab0 * b2f(q0) + ab1 * b2f(q1) + ab2 * b2f(q2) + ab3 * b2f(q3);
    }
  } else {
    // fallback: serial 3-pass (unreachable for this data size, kept for correctness)
    float m0 = -INFINITY, m1 = -INFINITY, m2 = -INFINITY, m3 = -INFINITY;
    for (int i = beg; i < end; ++i) {
      int e = elist[i];
      float4 av = *(const float4*)&a4buf[e * 4];
      m0 = fmaxf(m0, av.x); m1 = fmaxf(m1, av.y); m2 = fmaxf(m2, av.z); m3 = fmaxf(m3, av.w);
    }
    float d0 = 0.f, d1 = 0.f, d2 = 0.f, d3 = 0.f;
    for (int i = beg; i < end; ++i) {
      int e = elist[i];
      float4 av = *(const float4*)&a4buf[e * 4];
      d0 += __expf(av.x - m0); d1 += __expf(av.y - m1);
      d2 += __expf(av.z - m2); d3 += __expf(av.w - m3);
    }
    d0 = 1.f / (d0 + 1e-16f); d1 = 1.f / (d1 + 1e-16f);
    d2 = 1.f / (d2 + 1e-16f); d3 = 1.f / (d3 + 1e-16f);
    for (int i = beg; i < end; ++i) {
      int e = elist[i];
      float4 av = *(const float4*)&a4buf[e * 4];
      float ab = 0.25f * (__expf(av.x - m0) * d0 + __expf(av.y - m1) * d1 +
                          __expf(av.z - m2) * d2 + __expf(av.w - m3) * d3);
      int s = esrc[e];
      ushort2 xu = *(const ushort2*)&xh[(size_t)s * HID + lane * 2];
      ax += ab * b2f(xu.x); ay += ab * b2f(xu.y);
      if (lane < 16) ae += ab * b2f(eaeeB[(size_t)e * 16 + lane]);
    }
  }

  *(ushort2*)&agg[rb + lane * 2] = make_ushort2(f2b(ax), f2b(ay));
  if (lane < 16) agg[rb + 128 + lane] = f2b(ae);
  if (lane < 24) *(ushort2*)&agg[rb + 144 + lane * 2] = make_ushort2(0, 0);
}

// ---------------- launch ----------------
extern "C" void kernel_launch(void* const* d_in, const int* in_sizes, int n_in,
                              void* d_out, int out_size, void* d_ws, size_t ws_size,
                              hipStream_t stream)
{
  const float* x_gen = (const float*)d_in[0];
  const float* x_bus = (const float*)d_in[1];
  const float* x_res = (const float*)d_in[2];
  const int* eip = (const int*)d_in[3];
  const int* eis = (const int*)d_in[4];
  const int* eit = (const int*)d_in[5];
  const int* eib = (const int*)d_in[6];
  const float* eap = (const float*)d_in[7];
  const float* eas = (const float*)d_in[8];
  const float* eat = (const float*)d_in[9];
  const float* eab = (const float*)d_in[10];
  const float* pW_gen = (const float*)d_in[11];
  const float* pb_gen = (const float*)d_in[12];
  const float* pW_bus = (const float*)d_in[13];
  const float* pb_bus = (const float*)d_in[14];
  const float* pW_res = (const float*)d_in[15];
  const float* pb_res = (const float*)d_in[16];

  float* out = (float*)d_out;

  char* p = (char*)d_ws;
  auto alloc = [&](size_t bytes) -> void* {
    void* r = (void*)p;
    p += (bytes + 255) & ~(size_t)255;
    return r;
  };
  int* esrc    = (int*)alloc((size_t)ETOT * 4);
  int* edst    = (int*)alloc((size_t)ETOT * 4);
  float* ea_all = (float*)alloc((size_t)ETOT * 2 * 4);
  int* cnt     = (int*)alloc((size_t)NTOT * 4);
  int* fill    = (int*)alloc((size_t)NTOT * 4);
  int* rp      = (int*)alloc((size_t)(NTOT + 1) * 4);
  int* bsum    = (int*)alloc(1024 * 4);
  int* elist   = (int*)alloc((size_t)ETOT * 4);
  ushort* Wt   = (ushort*)alloc((size_t)245760 * 2);
  float* xA    = (float*)alloc((size_t)NTOT * HID * 4);    // fp32 x2 ping
  ushort* x_bf = (ushort*)alloc((size_t)NTOT * HID * 2);
  ushort* xh_bf = (ushort*)alloc((size_t)NTOT * HID * 2);
  float* sd    = (float*)alloc((size_t)NTOT * 4 * 4);
  float* ss    = (float*)alloc((size_t)NTOT * 4 * 4);
  ushort* eaeeB = (ushort*)alloc((size_t)ETOT * 16 * 2);
  float* a4buf = (float*)alloc((size_t)ETOT * 4 * 4);
  ushort* agg  = (ushort*)alloc((size_t)NTOT * 192 * 2);
  float* tconst = (float*)alloc(64);

  // ---- CSR build ----
  hipMemsetAsync(cnt, 0, (size_t)NTOT * 4, stream);
  hipMemsetAsync(fill, 0, (size_t)NTOT * 4, stream);
  k_setup_edges<<<EB, 256, 0, stream>>>(eip, eis, eit, eib, eap, eas, eat, eab, esrc, edst, ea_all, cnt);
  k_scan1<<<NB_SCAN, 256, 0, stream>>>(cnt, rp, bsum);
  k_scan2<<<1, 1024, 0, stream>>>(bsum, NB_SCAN);
  k_scan3<<<NB_SCAN, 256, 0, stream>>>(rp, bsum);
  k_scatter<<<EB, 256, 0, stream>>>(edst, rp, fill, elist);

  // ---- weight conversion ----
  k_convW<<<960, 256, 0, stream>>>(pW_gen, pW_bus, pW_res,
      (const float*)d_in[17], (const float*)d_in[22],
      (const float*)d_in[23], (const float*)d_in[28],
      (const float*)d_in[29], (const float*)d_in[34], Wt);

  const int NB0 = (NGEN + 127) / 128, NB1 = (NBUS + 127) / 128, NB2 = (NRES + 127) / 128;
  const int NBT = NB0 + NB1 + NB2;   // 391+625+79 = 1095

  // ---- input projections -> x_bf (bf16 only; x0 fp32 never needed) ----
  {
    Seg s0{x_gen, Wt + 0,     pb_gen, 39, 39, NGEN, NB0, 0};
    Seg s1{x_bus, Wt + 8192,  pb_bus, 16, 16, NBUS, NB1, NGEN};
    Seg s2{x_res, Wt + 16384, pb_res, 16, 16, NRES, NB2, NGEN + NBUS};
    k_mgemm3<0><<<NBT, 256, 0, stream>>>(s0, s1, s2, 64, x_bf);
  }

  for (int l = 0; l < 3; ++l) {
    const float* hb   = (const float*)d_in[18 + l * 6];
    const float* ete  = (const float*)d_in[19 + l * 6];
    const float* eae  = (const float*)d_in[20 + l * 6];
    const float* attw = (const float*)d_in[21 + l * 6];
    const ushort* WtH = Wt + 24576 + l * 73728;
    const ushort* WtL = Wt + 24576 + l * 73728 + 49152;

    const float* resid = (l == 0) ? nullptr : (l == 1) ? out : xA;
    float* xoutf       = (l == 0) ? out : (l == 1) ? xA : out;
    ushort* xoutb      = (l == 2) ? nullptr : x_bf;

    // HeteroLinear: x_bf -> xh_bf (single dispatch, 3 segments)
    {
      Seg s0{x_bf,                              WtH,         hb,       128, 128, NGEN, NB0, 0};
      Seg s1{x_bf + (size_t)NGEN * HID,         WtH + 16384, hb + 128, 128, 128, NBUS, NB1, NGEN};
      Seg s2{x_bf + (size_t)(NGEN + NBUS) * HID, WtH + 32768, hb + 256, 128, 128, NRES, NB2, NGEN + NBUS};
      k_mgemm3<1><<<NBT, 256, 0, stream>>>(s0, s1, s2, 128, xh_bf);
    }

    k_tconst<<<1, 64, 0, stream>>>(ete, attw, tconst);
    k_attproj<<<WB, 256, 0, stream>>>(xh_bf, attw, sd, ss);
    k_edge<<<EB, 256, 0, stream>>>(esrc, edst, ea_all, eae, attw, tconst, sd, ss, eaeeB, a4buf);
    k_aggregate<<<WB, 256, 0, stream>>>(rp, elist, esrc, a4buf, eaeeB, xh_bf, agg);

    // xout = relu(agg @ linw) + resid
    k_mgemm<<<(NTOT + 127) / 128, 256, 0, stream>>>(agg, 192, WtL, 192, resid, xoutf, xoutb, NTOT);
  }
}